// Round 4
// baseline (327.389 us; speedup 1.0000x reference)
//
#include <hip/hip_runtime.h>
#include <hip/hip_cooperative_groups.h>
#include <math.h>

namespace cg = cooperative_groups;

#define BB   128
#define CC   5
#define PP   5
#define LL   5
#define DD   128
#define NSEQ 640
#define GATES 512
#define IN0  384
#define HPAD 136

typedef __attribute__((ext_vector_type(8))) short short8;   // 8 bf16
typedef __attribute__((ext_vector_type(4))) float f32x4;    // MFMA C/D
typedef __attribute__((address_space(1))) const unsigned int as1_uint;
typedef __attribute__((address_space(3))) unsigned int as3_uint;

__device__ __forceinline__ float sigf(float x){ return 1.0f/(1.0f+__expf(-x)); }
__device__ __forceinline__ float tanhfast(float x){ return 1.0f - 2.0f/(__expf(2.0f*x)+1.0f); }

__device__ __forceinline__ unsigned short f2bf(float x){
    union { float f; unsigned u; } v; v.f = x;
    unsigned r = v.u + 0x7FFF + ((v.u >> 16) & 1);   // RNE
    return (unsigned short)(r >> 16);
}

// pt values with t<=p (15 of 25)
__device__ __constant__ int c_ptmap[15] = {0,5,6,10,11,12,15,16,17,18,20,21,22,23,24};

// ============================================================================
// MEGA: one cooperative kernel, 200 blocks x 512 threads, 3 grid.sync()s.
// phase1 = stage0 work (grid-stride), phase2 = ih0 GEMM (600 x 128-row tiles,
// 3/block, Bs persistent per combo), phase3 = fused 2-layer LSTM + final.
// ============================================================================
__global__ __launch_bounds__(512, 2) void mega_kernel(
    const float* __restrict__ Wih0, const float* __restrict__ Whh0,
    const float* __restrict__ Wih1, const float* __restrict__ Whh1,
    const float* __restrict__ bih0, const float* __restrict__ bhh0,
    const float* __restrict__ bih1, const float* __restrict__ bhh1,
    unsigned short* __restrict__ F0, unsigned short* __restrict__ F1,
    unsigned short* __restrict__ F2, unsigned short* __restrict__ F3,
    float* __restrict__ b0, float* __restrict__ b1c,
    float* __restrict__ psum,
    const int* __restrict__ user_index,
    const int* __restrict__ tpath, const int* __restrict__ ttype,
    const int* __restrict__ trel,
    const float* __restrict__ entity_emb, const float* __restrict__ relation_emb,
    const float* __restrict__ user_emb, const float* __restrict__ news_emb,
    const float* __restrict__ type_emb,
    unsigned short* __restrict__ X, const int* __restrict__ cand,
    float* __restrict__ embv,
    const float* __restrict__ W1, const float* __restrict__ b1v,
    const float* __restrict__ W2, const float* __restrict__ b2v,
    float* __restrict__ G0c, float* __restrict__ out)
{
    // F1s region is time-shared: phase2 Bs (48 KB), phase3 Whh0 slice (128 KB),
    // epilogue h1f/mlpb. Transitions are separated by grid.sync / barriers.
    __shared__ __align__(16) unsigned short F1s[4*32*512];   // 131072 B
    __shared__ unsigned short h0T[2][16*HPAD];               // 2x 4352 B
    __shared__ unsigned short h1T[2][16*HPAD];

    cg::grid_group grid = cg::this_grid();
    int bx = blockIdx.x, tid = threadIdx.x;
    int lane = tid & 63, w = tid >> 6;
    int r16 = lane & 15, qd = lane >> 4;

    // ---------------- phase 1: prep + gather + emb dots (grid-stride) -------
    const int P1 = 985*256;                 // prep items
    const int P2 = P1 + 15*NSEQ*48;         // + gather items
    const int NTOT = P2 + NSEQ*16;          // + dot items
    for (int it = bx*512 + tid; it < NTOT; it += 200*512){
        if (it < P1){
            int id = it;
            const int NF0 = PP*12*32*64;     // 122880
            const int NFH = PP*4*32*64;      // 40960
            if (id < NF0 + 3*NFH){
                const float* src; unsigned short* dst; int K, KT, fid;
                if (id < NF0){ src = Wih0; dst = F0; K = IN0; KT = 12; fid = id; }
                else {
                    int jx = id - NF0; int m = jx / NFH; fid = jx % NFH; K = DD; KT = 4;
                    src = (m==0)?Whh0:(m==1)?Wih1:Whh1;
                    dst = (m==0)?F1:(m==1)?F2:F3;
                }
                int ln = fid & 63; int rem = fid >> 6;
                int gt = rem & 31; rem >>= 5;
                int kt = rem % KT; int p = rem / KT;
                int g  = gt*16 + (ln & 15);
                int k0 = kt*32 + (ln >> 4)*8;
                const float* s = src + (size_t)(p*GATES + g)*K + k0;
                float4 x0 = *(const float4*)s;
                float4 x1 = *(const float4*)(s+4);
                uint4 o;
                o.x = f2bf(x0.x) | ((unsigned)f2bf(x0.y)<<16);
                o.y = f2bf(x0.z) | ((unsigned)f2bf(x0.w)<<16);
                o.z = f2bf(x1.x) | ((unsigned)f2bf(x1.y)<<16);
                o.w = f2bf(x1.z) | ((unsigned)f2bf(x1.w)<<16);
                *(uint4*)(dst + (size_t)fid*8) = o;
            } else {
                int jx = id - (NF0 + 3*NFH);
                if (jx < PP*GATES) b0[jx] = bih0[jx] + bhh0[jx];
                else if (jx < 2*PP*GATES){ int q = jx - PP*GATES; b1c[q] = bih1[q] + bhh1[q]; }
                else if (jx < 2*PP*GATES + NSEQ){ psum[jx - 2*PP*GATES] = 0.0f; }
            }
        } else if (it < P2){
            int id = it - P1;
            int ptIdx = id / (NSEQ*48); int rem = id % (NSEQ*48);
            int n = rem / 48, q = rem % 48;
            int pt = c_ptmap[ptIdx];
            int p = pt / LL, t = pt % LL;
            int b = n / CC, c = n % CC;
            int u = user_index[b];
            int base = ((u*CC + c)*PP + p)*LL + t;
            int col = q*8;
            const float* s;
            if (q < 16){
                int ty = ttype[base]; int pi = tpath[base];
                const float* e = (ty==0)?user_emb:(ty==1)?news_emb:entity_emb;
                s = e + (size_t)pi*DD + col;
            } else if (q < 32){
                s = type_emb + (size_t)ttype[base]*DD + (col-128);
            } else {
                s = relation_emb + (size_t)trel[base]*DD + (col-256);
            }
            float4 x0 = *(const float4*)s, x1 = *(const float4*)(s+4);
            uint4 o;
            o.x = f2bf(x0.x) | ((unsigned)f2bf(x0.y)<<16);
            o.y = f2bf(x0.z) | ((unsigned)f2bf(x0.w)<<16);
            o.z = f2bf(x1.x) | ((unsigned)f2bf(x1.y)<<16);
            o.w = f2bf(x1.z) | ((unsigned)f2bf(x1.w)<<16);
            *(uint4*)(X + (size_t)(pt*NSEQ + n)*IN0 + col) = o;
        } else {
            int id = it - P2;                 // 640*16 items
            int n = id >> 4, k = id & 15;
            int b = n / CC;
            int nb = cand[n];
            int u = user_index[b];
            const float4* ne = (const float4*)(news_emb + (size_t)nb*DD + k*8);
            const float4* ue = (const float4*)(user_emb + (size_t)u*DD + k*8);
            float4 a0 = ne[0], a1 = ne[1], u0 = ue[0], u1 = ue[1];
            float v = a0.x*u0.x + a0.y*u0.y + a0.z*u0.z + a0.w*u0.w
                    + a1.x*u1.x + a1.y*u1.y + a1.z*u1.z + a1.w*u1.w;
            #pragma unroll
            for (int off=8; off; off>>=1) v += __shfl_down(v, off, 16);
            if (k == 0) embv[n] = v;
        }
    }
    grid.sync();

    // ---------------- phase 2: G0c = X @ Wih0^T, 600 tiles (128 rows), 3/blk -
    {
        unsigned short* Bs = F1s;            // 48 KB alias
        int curcid = -1;
        int half = tid >> 8;                 // 0/1, wave-uniform
        int t255 = tid & 255;
        #pragma unroll
        for (int ii=0; ii<3; ii++){
            int T = bx*3 + ii;               // < 600
            int cid = T/5, m128 = T%5;
            int ptIdx = cid >> 3, nch = cid & 7;
            int pt = c_ptmap[ptIdx];
            int p = pt / LL;
            if (cid != curcid){
                __syncthreads();             // all waves done with old Bs
                const unsigned short* Fp = F0 + (((size_t)p*12)*32 + nch*4)*512;
                #pragma unroll
                for (int v=0; v<6; v++){
                    int jj = v*2 + half;
                    __builtin_amdgcn_global_load_lds(
                        (as1_uint*)(Fp + (size_t)jj*32*512 + t255*8),
                        (as3_uint*)(Bs + jj*2048 + (t255 & 192)*8),
                        16, 0, 0);
                }
                __syncthreads();             // drains global_load_lds
                curcid = cid;
            }
            f32x4 acc[4];
            #pragma unroll
            for (int i=0;i<4;i++) acc[i] = (f32x4)0.0f;
            const unsigned short* Xb = X + ((size_t)pt*NSEQ + m128*128 + w*16 + r16)*IN0 + qd*8;
            #pragma unroll
            for (int kt=0; kt<12; kt++){
                short8 a = *(const short8*)(Xb + kt*32);
                #pragma unroll
                for (int i=0;i<4;i++){
                    short8 bfr = *(const short8*)(Bs + (kt*4+i)*512 + lane*8);
                    acc[i] = __builtin_amdgcn_mfma_f32_16x16x32_bf16(a, bfr, acc[i], 0,0,0);
                }
            }
            int tile16 = pt*40 + m128*8 + w;
            float* dst = G0c + (((size_t)tile16*32 + nch*4)*64 + lane)*4;
            #pragma unroll
            for (int i=0;i<4;i++)
                *(f32x4*)(dst + (size_t)i*256) = acc[i];
        }
    }
    grid.sync();

    // ---------------- phase 3: fused 2-layer LSTM (lstm_v8 body) ------------
    {
        float* h1f  = (float*)F1s;               // [16][132]
        float* mlpb = (float*)(F1s + 16*132*2);  // [16][17]
        int pL = bx / 40, nt = bx % 40;
        int n0 = nt*16;
        int j = w*16 + r16;

        if (pL > 0){
            const unsigned short* F1g = F1 + (size_t)pL*4*32*512;
            #pragma unroll
            for (int v=0; v<16; v++){
                __builtin_amdgcn_global_load_lds(
                    (as1_uint*)(F1g + (size_t)v*4096 + tid*8),
                    (as3_uint*)(F1s + v*4096 + (tid & 448)*8),
                    16, 0, 0);
            }
        }

        short8 f2r[16], f3r[16];
        {
            const unsigned short* F2p = F2 + (size_t)pL*4*32*512 + lane*8;
            const unsigned short* F3p = F3 + (size_t)pL*4*32*512 + lane*8;
            #pragma unroll
            for (int kt=0; kt<4; kt++)
                #pragma unroll
                for (int i=0;i<4;i++){
                    f2r[kt*4+i] = *(const short8*)(F2p + (size_t)(kt*32 + i*8 + w)*512);
                    f3r[kt*4+i] = *(const short8*)(F3p + (size_t)(kt*32 + i*8 + w)*512);
                }
        }
        float bL0[4], bL1[4];
        #pragma unroll
        for (int i=0;i<4;i++){
            int col = (i*8 + w)*16 + r16;
            bL0[i] = b0[pL*GATES + col];
            bL1[i] = b1c[pL*GATES + col];
        }

        f32x4 pf[4];
        {
            const float* slab = G0c + (size_t)((pL*LL + 0)*40 + nt)*8192;
            #pragma unroll
            for (int i=0;i<4;i++) pf[i] = *(const f32x4*)(slab + ((i*8+w)*64 + lane)*4);
        }
        float c0s[4] = {0,0,0,0}, c1s[4] = {0,0,0,0};

        for (int t=0; t<=pL; t++){
            const int cur = t & 1, prv = cur ^ 1;
            f32x4 acc[4];
            #pragma unroll
            for (int i=0;i<4;i++){
                f32x4 a = pf[i]; float bb = bL0[i];
                a[0]+=bb; a[1]+=bb; a[2]+=bb; a[3]+=bb; acc[i]=a;
            }
            if (t < pL){
                const float* ns = G0c + (size_t)((pL*LL + t + 1)*40 + nt)*8192;
                #pragma unroll
                for (int i=0;i<4;i++) pf[i] = *(const f32x4*)(ns + ((i*8+w)*64 + lane)*4);
            }
            if (t > 0){
                #pragma unroll
                for (int kt=0; kt<4; kt++){
                    short8 a = *(const short8*)(&h0T[prv][0] + r16*HPAD + kt*32 + qd*8);
                    #pragma unroll
                    for (int i=0;i<4;i++){
                        short8 bfr = *(const short8*)(F1s + (size_t)(kt*32 + i*8 + w)*512 + lane*8);
                        acc[i] = __builtin_amdgcn_mfma_f32_16x16x32_bf16(a, bfr, acc[i], 0,0,0);
                    }
                }
            }
            #pragma unroll
            for (int v=0; v<4; v++){
                float cc = sigf(acc[1][v])*c0s[v] + sigf(acc[0][v])*tanhfast(acc[2][v]);
                c0s[v] = cc;
                h0T[cur][(qd*4+v)*HPAD + j] = f2bf(sigf(acc[3][v])*tanhfast(cc));
            }
            __syncthreads();   // h0T[cur] visible; drains F1s stage (t=0); h1T[t-1]
            #pragma unroll
            for (int i=0;i<4;i++){
                float bb = bL1[i];
                f32x4 a; a[0]=bb; a[1]=bb; a[2]=bb; a[3]=bb; acc[i]=a;
            }
            #pragma unroll
            for (int kt=0; kt<4; kt++){
                short8 a = *(const short8*)(&h0T[cur][0] + r16*HPAD + kt*32 + qd*8);
                #pragma unroll
                for (int i=0;i<4;i++)
                    acc[i] = __builtin_amdgcn_mfma_f32_16x16x32_bf16(a, f2r[kt*4+i], acc[i], 0,0,0);
            }
            if (t > 0){
                #pragma unroll
                for (int kt=0; kt<4; kt++){
                    short8 a = *(const short8*)(&h1T[prv][0] + r16*HPAD + kt*32 + qd*8);
                    #pragma unroll
                    for (int i=0;i<4;i++)
                        acc[i] = __builtin_amdgcn_mfma_f32_16x16x32_bf16(a, f3r[kt*4+i], acc[i], 0,0,0);
                }
            }
            #pragma unroll
            for (int v=0; v<4; v++){
                float cc = sigf(acc[1][v])*c1s[v] + sigf(acc[0][v])*tanhfast(acc[2][v]);
                c1s[v] = cc;
                float hh = sigf(acc[3][v])*tanhfast(cc);
                if (t < pL) h1T[cur][(qd*4+v)*HPAD + j] = f2bf(hh);
                else        h1f[(qd*4+v)*132 + j] = hh;
            }
        }
        __syncthreads();
        if (tid < 256){
            int rr = tid & 15, hc = tid >> 4;
            const float4* w1r = (const float4*)(W1 + hc*DD);
            const float4* hrow = (const float4*)(h1f + rr*132);
            float a0 = b1v[hc], a1 = 0.0f, a2 = 0.0f, a3 = 0.0f;
            #pragma unroll
            for (int k=0;k<32;k++){
                float4 wv = w1r[k];
                float4 hv = hrow[k];
                a0 = fmaf(hv.x, wv.x, a0);
                a1 = fmaf(hv.y, wv.y, a1);
                a2 = fmaf(hv.z, wv.z, a2);
                a3 = fmaf(hv.w, wv.w, a3);
            }
            mlpb[hc*17 + rr] = fmaxf((a0+a1)+(a2+a3), 0.0f);
        }
        __syncthreads();
        if (tid < 16){
            float s = b2v[0];
            #pragma unroll
            for (int h=0;h<16;h++) s = fmaf(mlpb[h*17 + tid], W2[h], s);
            atomicAdd(&psum[n0 + tid], 0.2f*sigf(s));
        }
    }
    grid.sync();   // acquire: psum atomics + embv visible to block 0

    // ---------------- final: emb_score + running mean ------------------------
    if (bx == 0 && tid < BB){
        float cum = 0.0f;
        #pragma unroll
        for (int c=0;c<CC;c++){
            cum += psum[tid*CC + c];
            out[tid*CC + c] = sigf(embv[tid*CC + c]) + cum/(float)(c+1);
        }
    }
}

// ============================================================================
// FALLBACK PATH (round-3 proven three-dispatch pipeline), used only if the
// cooperative launch is rejected (e.g. graph-capture incompatibility).
// ============================================================================
__global__ void stage0_kernel(const float* __restrict__ Wih0, const float* __restrict__ Whh0,
                              const float* __restrict__ Wih1, const float* __restrict__ Whh1,
                              const float* __restrict__ bih0, const float* __restrict__ bhh0,
                              const float* __restrict__ bih1, const float* __restrict__ bhh1,
                              unsigned short* __restrict__ F0, unsigned short* __restrict__ F1,
                              unsigned short* __restrict__ F2, unsigned short* __restrict__ F3,
                              float* __restrict__ b0, float* __restrict__ b1c,
                              float* __restrict__ psum,
                              const int* __restrict__ user_index,
                              const int* __restrict__ tpath, const int* __restrict__ ttype,
                              const int* __restrict__ trel,
                              const float* __restrict__ entity_emb, const float* __restrict__ relation_emb,
                              const float* __restrict__ user_emb, const float* __restrict__ news_emb,
                              const float* __restrict__ type_emb,
                              unsigned short* __restrict__ X,
                              const int* __restrict__ cand,
                              float* __restrict__ embv, int* __restrict__ ctr){
    int bx = blockIdx.x;
    if (bx < 985){
        int id = bx*256 + threadIdx.x;
        const int NF0 = PP*12*32*64;
        const int NFH = PP*4*32*64;
        if (id < NF0 + 3*NFH){
            const float* src; unsigned short* dst; int K, KT, fid;
            if (id < NF0){ src = Wih0; dst = F0; K = IN0; KT = 12; fid = id; }
            else {
                int j = id - NF0; int m = j / NFH; fid = j % NFH; K = DD; KT = 4;
                src = (m==0)?Whh0:(m==1)?Wih1:Whh1;
                dst = (m==0)?F1:(m==1)?F2:F3;
            }
            int lane = fid & 63; int rem = fid >> 6;
            int gt = rem & 31; rem >>= 5;
            int kt = rem % KT; int p = rem / KT;
            int g  = gt*16 + (lane & 15);
            int k0 = kt*32 + (lane >> 4)*8;
            const float* s = src + (size_t)(p*GATES + g)*K + k0;
            float4 x0 = *(const float4*)s;
            float4 x1 = *(const float4*)(s+4);
            uint4 o;
            o.x = f2bf(x0.x) | ((unsigned)f2bf(x0.y)<<16);
            o.y = f2bf(x0.z) | ((unsigned)f2bf(x0.w)<<16);
            o.z = f2bf(x1.x) | ((unsigned)f2bf(x1.y)<<16);
            o.w = f2bf(x1.z) | ((unsigned)f2bf(x1.w)<<16);
            *(uint4*)(dst + (size_t)fid*8) = o;
        } else {
            int j = id - (NF0 + 3*NFH);
            if (j < PP*GATES) b0[j] = bih0[j] + bhh0[j];
            else if (j < 2*PP*GATES){ int q = j - PP*GATES; b1c[q] = bih1[q] + bhh1[q]; }
            else if (j < 2*PP*GATES + NSEQ){ psum[j - 2*PP*GATES] = 0.0f; }
            else if (j == 2*PP*GATES + NSEQ){ ctr[0] = 0; }
        }
    } else if (bx < 2785){
        int id = (bx - 985)*256 + threadIdx.x;
        if (id >= 15*NSEQ*48) return;
        int ptIdx = id / (NSEQ*48); int rem = id % (NSEQ*48);
        int n = rem / 48, q = rem % 48;
        int pt = c_ptmap[ptIdx];
        int p = pt / LL, t = pt % LL;
        int b = n / CC, c = n % CC;
        int u = user_index[b];
        int base = ((u*CC + c)*PP + p)*LL + t;
        int col = q*8;
        const float* s;
        if (q < 16){
            int ty = ttype[base]; int pi = tpath[base];
            const float* e = (ty==0)?user_emb:(ty==1)?news_emb:entity_emb;
            s = e + (size_t)pi*DD + col;
        } else if (q < 32){
            s = type_emb + (size_t)ttype[base]*DD + (col-128);
        } else {
            s = relation_emb + (size_t)trel[base]*DD + (col-256);
        }
        float4 x0 = *(const float4*)s, x1 = *(const float4*)(s+4);
        uint4 o;
        o.x = f2bf(x0.x) | ((unsigned)f2bf(x0.y)<<16);
        o.y = f2bf(x0.z) | ((unsigned)f2bf(x0.w)<<16);
        o.z = f2bf(x1.x) | ((unsigned)f2bf(x1.y)<<16);
        o.w = f2bf(x1.z) | ((unsigned)f2bf(x1.w)<<16);
        *(uint4*)(X + (size_t)(pt*NSEQ + n)*IN0 + col) = o;
    } else {
        int id = (bx - 2785)*256 + threadIdx.x;
        int n = id >> 4, k = id & 15;
        int b = n / CC;
        int nb = cand[n];
        int u = user_index[b];
        const float4* ne = (const float4*)(news_emb + (size_t)nb*DD + k*8);
        const float4* ue = (const float4*)(user_emb + (size_t)u*DD + k*8);
        float4 a0 = ne[0], a1 = ne[1], u0 = ue[0], u1 = ue[1];
        float v = a0.x*u0.x + a0.y*u0.y + a0.z*u0.z + a0.w*u0.w
                + a1.x*u1.x + a1.y*u1.y + a1.z*u1.z + a1.w*u1.w;
        #pragma unroll
        for (int off=8; off; off>>=1) v += __shfl_down(v, off, 16);
        if (k == 0) embv[n] = v;
    }
}

__global__ __launch_bounds__(256) void gemm_ih0_v5(const unsigned short* __restrict__ X,
                                                   const unsigned short* __restrict__ F0,
                                                   float* __restrict__ G0c){
    __shared__ unsigned short Bs[12*4*512];
    int bx = blockIdx.x;
    int nch = bx & 7;
    int m64 = (bx >> 3) % 10;
    int pt  = c_ptmap[bx / 80];
    int p = pt / LL;
    int tid = threadIdx.x, lane = tid & 63, w = tid >> 6;
    int r16 = lane & 15, qd = lane >> 4;

    const unsigned short* Fp = F0 + (((size_t)p*12)*32 + nch*4)*512;
    uint4 breg[12];
    #pragma unroll
    for (int j=0;j<12;j++)
        breg[j] = *(const uint4*)(Fp + (size_t)j*32*512 + tid*8);
    #pragma unroll
    for (int j=0;j<12;j++)
        *(uint4*)(Bs + j*2048 + tid*8) = breg[j];
    __syncthreads();

    f32x4 acc[4];
    #pragma unroll
    for (int i=0;i<4;i++) acc[i] = (f32x4)0.0f;
    const unsigned short* Xb = X + ((size_t)pt*NSEQ + m64*64 + w*16 + r16)*IN0 + qd*8;
    #pragma unroll
    for (int kt=0; kt<12; kt++){
        short8 a = *(const short8*)(Xb + kt*32);
        #pragma unroll
        for (int i=0;i<4;i++){
            short8 bfr = *(const short8*)(Bs + (kt*4+i)*512 + lane*8);
            acc[i] = __builtin_amdgcn_mfma_f32_16x16x32_bf16(a, bfr, acc[i], 0,0,0);
        }
    }
    int tile16 = pt*40 + m64*4 + w;
    float* dst = G0c + (((size_t)tile16*32 + nch*4)*64 + lane)*4;
    #pragma unroll
    for (int i=0;i<4;i++)
        *(f32x4*)(dst + (size_t)i*256) = acc[i];
}

__global__ __launch_bounds__(512, 2) void lstm_v8(
    const float* __restrict__ G0c,
    const unsigned short* __restrict__ F1,
    const unsigned short* __restrict__ F2,
    const unsigned short* __restrict__ F3,
    const float* __restrict__ b0, const float* __restrict__ b1c,
    const float* __restrict__ W1, const float* __restrict__ b1v,
    const float* __restrict__ W2, const float* __restrict__ b2v,
    float* __restrict__ psum,
    const float* __restrict__ embv, int* __restrict__ ctr,
    float* __restrict__ out){
    __shared__ __align__(16) unsigned short F1s[4*32*512];
    __shared__ unsigned short h0T[2][16*HPAD];
    __shared__ unsigned short h1T[2][16*HPAD];
    __shared__ int lastFlag;
    float* h1f  = (float*)F1s;
    float* mlpb = (float*)(F1s + 16*132*2);

    int p = blockIdx.x / 40, nt = blockIdx.x % 40;
    int n0 = nt*16;
    int tid = threadIdx.x;
    int lane = tid & 63, w = tid >> 6;
    int r16 = lane & 15, qd = lane >> 4;
    int j = w*16 + r16;

    if (p > 0){
        const unsigned short* F1g = F1 + (size_t)p*4*32*512;
        #pragma unroll
        for (int v=0; v<16; v++){
            __builtin_amdgcn_global_load_lds(
                (as1_uint*)(F1g + (size_t)v*4096 + tid*8),
                (as3_uint*)(F1s + v*4096 + (tid & 448)*8),
                16, 0, 0);
        }
    }

    short8 f2r[16], f3r[16];
    {
        const unsigned short* F2p = F2 + (size_t)p*4*32*512 + lane*8;
        const unsigned short* F3p = F3 + (size_t)p*4*32*512 + lane*8;
        #pragma unroll
        for (int kt=0; kt<4; kt++)
            #pragma unroll
            for (int i=0;i<4;i++){
                f2r[kt*4+i] = *(const short8*)(F2p + (size_t)(kt*32 + i*8 + w)*512);
                f3r[kt*4+i] = *(const short8*)(F3p + (size_t)(kt*32 + i*8 + w)*512);
            }
    }
    float bL0[4], bL1[4];
    #pragma unroll
    for (int i=0;i<4;i++){
        int col = (i*8 + w)*16 + r16;
        bL0[i] = b0[p*GATES + col];
        bL1[i] = b1c[p*GATES + col];
    }

    f32x4 pf[4];
    {
        const float* slab = G0c + (size_t)((p*LL + 0)*40 + nt)*8192;
        #pragma unroll
        for (int i=0;i<4;i++) pf[i] = *(const f32x4*)(slab + ((i*8+w)*64 + lane)*4);
    }
    float c0s[4] = {0,0,0,0}, c1s[4] = {0,0,0,0};

    for (int t=0; t<=p; t++){
        const int cur = t & 1, prv = cur ^ 1;
        f32x4 acc[4];
        #pragma unroll
        for (int i=0;i<4;i++){
            f32x4 a = pf[i]; float bb = bL0[i];
            a[0]+=bb; a[1]+=bb; a[2]+=bb; a[3]+=bb; acc[i]=a;
        }
        if (t < p){
            const float* ns = G0c + (size_t)((p*LL + t + 1)*40 + nt)*8192;
            #pragma unroll
            for (int i=0;i<4;i++) pf[i] = *(const f32x4*)(ns + ((i*8+w)*64 + lane)*4);
        }
        if (t > 0){
            #pragma unroll
            for (int kt=0; kt<4; kt++){
                short8 a = *(const short8*)(&h0T[prv][0] + r16*HPAD + kt*32 + qd*8);
                #pragma unroll
                for (int i=0;i<4;i++){
                    short8 bfr = *(const short8*)(F1s + (size_t)(kt*32 + i*8 + w)*512 + lane*8);
                    acc[i] = __builtin_amdgcn_mfma_f32_16x16x32_bf16(a, bfr, acc[i], 0,0,0);
                }
            }
        }
        #pragma unroll
        for (int v=0; v<4; v++){
            float cc = sigf(acc[1][v])*c0s[v] + sigf(acc[0][v])*tanhfast(acc[2][v]);
            c0s[v] = cc;
            h0T[cur][(qd*4+v)*HPAD + j] = f2bf(sigf(acc[3][v])*tanhfast(cc));
        }
        __syncthreads();
        #pragma unroll
        for (int i=0;i<4;i++){
            float bb = bL1[i];
            f32x4 a; a[0]=bb; a[1]=bb; a[2]=bb; a[3]=bb; acc[i]=a;
        }
        #pragma unroll
        for (int kt=0; kt<4; kt++){
            short8 a = *(const short8*)(&h0T[cur][0] + r16*HPAD + kt*32 + qd*8);
            #pragma unroll
            for (int i=0;i<4;i++)
                acc[i] = __builtin_amdgcn_mfma_f32_16x16x32_bf16(a, f2r[kt*4+i], acc[i], 0,0,0);
        }
        if (t > 0){
            #pragma unroll
            for (int kt=0; kt<4; kt++){
                short8 a = *(const short8*)(&h1T[prv][0] + r16*HPAD + kt*32 + qd*8);
                #pragma unroll
                for (int i=0;i<4;i++)
                    acc[i] = __builtin_amdgcn_mfma_f32_16x16x32_bf16(a, f3r[kt*4+i], acc[i], 0,0,0);
            }
        }
        #pragma unroll
        for (int v=0; v<4; v++){
            float cc = sigf(acc[1][v])*c1s[v] + sigf(acc[0][v])*tanhfast(acc[2][v]);
            c1s[v] = cc;
            float hh = sigf(acc[3][v])*tanhfast(cc);
            if (t < p) h1T[cur][(qd*4+v)*HPAD + j] = f2bf(hh);
            else       h1f[(qd*4+v)*132 + j] = hh;
        }
    }
    __syncthreads();
    if (tid < 256){
        int rr = tid & 15, hc = tid >> 4;
        const float4* w1r = (const float4*)(W1 + hc*DD);
        const float4* hrow = (const float4*)(h1f + rr*132);
        float a0 = b1v[hc], a1 = 0.0f, a2 = 0.0f, a3 = 0.0f;
        #pragma unroll
        for (int k=0;k<32;k++){
            float4 wv = w1r[k];
            float4 hv = hrow[k];
            a0 = fmaf(hv.x, wv.x, a0);
            a1 = fmaf(hv.y, wv.y, a1);
            a2 = fmaf(hv.z, wv.z, a2);
            a3 = fmaf(hv.w, wv.w, a3);
        }
        mlpb[hc*17 + rr] = fmaxf((a0+a1)+(a2+a3), 0.0f);
    }
    __syncthreads();
    if (tid < 16){
        float s = b2v[0];
        #pragma unroll
        for (int h=0;h<16;h++) s = fmaf(mlpb[h*17 + tid], W2[h], s);
        atomicAdd(&psum[n0 + tid], 0.2f*sigf(s));
        __threadfence();
    }
    __syncthreads();
    if (tid == 0){
        int old = atomicAdd(ctr, 1);
        lastFlag = (old == 199);
    }
    __syncthreads();
    if (!lastFlag) return;
    float* ps = (float*)F1s;
    for (int i = tid; i < NSEQ; i += 512)
        ps[i] = atomicAdd(&psum[i], 0.0f);
    __syncthreads();
    if (tid < BB){
        float cum = 0.0f;
        #pragma unroll
        for (int c=0;c<CC;c++){
            cum += ps[tid*CC + c];
            out[tid*CC + c] = sigf(embv[tid*CC + c]) + cum/(float)(c+1);
        }
    }
}

extern "C" void kernel_launch(void* const* d_in, const int* in_sizes, int n_in,
                              void* d_out, int out_size, void* d_ws, size_t ws_size,
                              hipStream_t stream){
    const int* cand        = (const int*)d_in[0];
    const int* uidx        = (const int*)d_in[1];
    const int* tpath       = (const int*)d_in[2];
    const int* ttype       = (const int*)d_in[3];
    const int* trel        = (const int*)d_in[4];
    const float* entity_emb   = (const float*)d_in[5];
    const float* relation_emb = (const float*)d_in[6];
    const float* user_emb     = (const float*)d_in[7];
    const float* news_emb     = (const float*)d_in[8];
    const float* type_emb     = (const float*)d_in[9];
    const float* Wih0 = (const float*)d_in[10];
    const float* Whh0 = (const float*)d_in[11];
    const float* bih0 = (const float*)d_in[12];
    const float* bhh0 = (const float*)d_in[13];
    const float* Wih1 = (const float*)d_in[14];
    const float* Whh1 = (const float*)d_in[15];
    const float* bih1 = (const float*)d_in[16];
    const float* bhh1 = (const float*)d_in[17];
    const float* W1 = (const float*)d_in[18];
    const float* b1 = (const float*)d_in[19];
    const float* W2 = (const float*)d_in[20];
    const float* b2 = (const float*)d_in[21];
    float* out = (float*)d_out;

    char* ws = (char*)d_ws;
    unsigned short* F0 = (unsigned short*)ws;  ws += (size_t)PP*12*32*512*2;
    unsigned short* F1 = (unsigned short*)ws;  ws += (size_t)PP*4*32*512*2;
    unsigned short* F2 = (unsigned short*)ws;  ws += (size_t)PP*4*32*512*2;
    unsigned short* F3 = (unsigned short*)ws;  ws += (size_t)PP*4*32*512*2;
    float* b0  = (float*)ws;                   ws += PP*GATES*4;
    float* b1c = (float*)ws;                   ws += PP*GATES*4;
    unsigned short* X = (unsigned short*)ws;   ws += (size_t)PP*LL*NSEQ*IN0*2;
    float* G0c = (float*)ws;                   ws += (size_t)PP*LL*NSEQ*GATES*4;
    float* psum = (float*)ws;                  ws += NSEQ*4;
    float* embv = (float*)ws;                  ws += NSEQ*4;
    int*   ctr  = (int*)ws;                    ws += 4;

    void* kargs[] = {
        (void*)&Wih0, (void*)&Whh0, (void*)&Wih1, (void*)&Whh1,
        (void*)&bih0, (void*)&bhh0, (void*)&bih1, (void*)&bhh1,
        (void*)&F0, (void*)&F1, (void*)&F2, (void*)&F3,
        (void*)&b0, (void*)&b1c, (void*)&psum,
        (void*)&uidx, (void*)&tpath, (void*)&ttype, (void*)&trel,
        (void*)&entity_emb, (void*)&relation_emb, (void*)&user_emb,
        (void*)&news_emb, (void*)&type_emb,
        (void*)&X, (void*)&cand, (void*)&embv,
        (void*)&W1, (void*)&b1, (void*)&W2, (void*)&b2,
        (void*)&G0c, (void*)&out
    };
    hipError_t err = hipLaunchCooperativeKernel((void*)mega_kernel,
                                                dim3(200), dim3(512),
                                                kargs, 0, stream);
    if (err != hipSuccess){
        // fallback: proven three-dispatch pipeline
        stage0_kernel<<<985+1800+40,256,0,stream>>>(Wih0,Whh0,Wih1,Whh1,bih0,bhh0,bih1,bhh1,
                                                 F0,F1,F2,F3,b0,b1c,psum,
                                                 uidx,tpath,ttype,trel,entity_emb,relation_emb,
                                                 user_emb,news_emb,type_emb,X,
                                                 cand,embv,ctr);
        gemm_ih0_v5<<<1200,256,0,stream>>>(X, F0, G0c);
        lstm_v8<<<200,512,0,stream>>>(G0c, F1, F2, F3, b0, b1c, W1, b1, W2, b2,
                                      psum, embv, ctr, out);
    }
}

// Round 5
// 220.522 us; speedup vs baseline: 1.4846x; 1.4846x over previous
//
#include <hip/hip_runtime.h>
#include <math.h>

#define BB   128
#define CC   5
#define PP   5
#define LL   5
#define DD   128
#define NSEQ 640
#define GATES 512
#define IN0  384
#define HPAD 136

typedef __attribute__((ext_vector_type(8))) short short8;   // 8 bf16
typedef __attribute__((ext_vector_type(4))) float f32x4;    // MFMA C/D
typedef __attribute__((address_space(1))) const unsigned int as1_uint;
typedef __attribute__((address_space(3))) unsigned int as3_uint;

__device__ __forceinline__ float sigf(float x){ return 1.0f/(1.0f+__expf(-x)); }
__device__ __forceinline__ float tanhfast(float x){ return 1.0f - 2.0f/(__expf(2.0f*x)+1.0f); }

__device__ __forceinline__ unsigned short f2bf(float x){
    union { float f; unsigned u; } v; v.f = x;
    unsigned r = v.u + 0x7FFF + ((v.u >> 16) & 1);   // RNE
    return (unsigned short)(r >> 16);
}

// pt values with t<=p (15 of 25)
__device__ __constant__ int c_ptmap[15] = {0,5,6,10,11,12,15,16,17,18,20,21,22,23,24};

// ---- stage0: prep (weights->frags, biases, psum=0, ctr=0) + gather_x
//      + emb-score dots, one dispatch ----------------------------------------
// blocks [0,985): prep; [985,2785): gather; [2785,2825): emb dots
__global__ void stage0_kernel(const float* __restrict__ Wih0, const float* __restrict__ Whh0,
                              const float* __restrict__ Wih1, const float* __restrict__ Whh1,
                              const float* __restrict__ bih0, const float* __restrict__ bhh0,
                              const float* __restrict__ bih1, const float* __restrict__ bhh1,
                              unsigned short* __restrict__ F0, unsigned short* __restrict__ F1,
                              unsigned short* __restrict__ F2, unsigned short* __restrict__ F3,
                              float* __restrict__ b0, float* __restrict__ b1c,
                              float* __restrict__ psum,
                              const int* __restrict__ user_index,
                              const int* __restrict__ tpath, const int* __restrict__ ttype,
                              const int* __restrict__ trel,
                              const float* __restrict__ entity_emb, const float* __restrict__ relation_emb,
                              const float* __restrict__ user_emb, const float* __restrict__ news_emb,
                              const float* __restrict__ type_emb,
                              unsigned short* __restrict__ X,
                              const int* __restrict__ cand,
                              float* __restrict__ embv, int* __restrict__ ctr){
    int bx = blockIdx.x;
    if (bx < 985){
        // ---------------- prep ----------------
        int id = bx*256 + threadIdx.x;
        const int NF0 = PP*12*32*64;     // 122880
        const int NFH = PP*4*32*64;      // 40960
        if (id < NF0 + 3*NFH){
            const float* src; unsigned short* dst; int K, KT, fid;
            if (id < NF0){ src = Wih0; dst = F0; K = IN0; KT = 12; fid = id; }
            else {
                int j = id - NF0; int m = j / NFH; fid = j % NFH; K = DD; KT = 4;
                src = (m==0)?Whh0:(m==1)?Wih1:Whh1;
                dst = (m==0)?F1:(m==1)?F2:F3;
            }
            int lane = fid & 63; int rem = fid >> 6;
            int gt = rem & 31; rem >>= 5;
            int kt = rem % KT; int p = rem / KT;
            int g  = gt*16 + (lane & 15);
            int k0 = kt*32 + (lane >> 4)*8;
            const float* s = src + (size_t)(p*GATES + g)*K + k0;
            float4 x0 = *(const float4*)s;
            float4 x1 = *(const float4*)(s+4);
            uint4 o;
            o.x = f2bf(x0.x) | ((unsigned)f2bf(x0.y)<<16);
            o.y = f2bf(x0.z) | ((unsigned)f2bf(x0.w)<<16);
            o.z = f2bf(x1.x) | ((unsigned)f2bf(x1.y)<<16);
            o.w = f2bf(x1.z) | ((unsigned)f2bf(x1.w)<<16);
            *(uint4*)(dst + (size_t)fid*8) = o;
        } else {
            int j = id - (NF0 + 3*NFH);
            if (j < PP*GATES) b0[j] = bih0[j] + bhh0[j];
            else if (j < 2*PP*GATES){ int q = j - PP*GATES; b1c[q] = bih1[q] + bhh1[q]; }
            else if (j < 2*PP*GATES + NSEQ){ psum[j - 2*PP*GATES] = 0.0f; }
            else if (j == 2*PP*GATES + NSEQ){ ctr[0] = 0; }
        }
    } else if (bx < 2785){
        // ---------------- gather (only t<=p slices) ----------------
        int id = (bx - 985)*256 + threadIdx.x;   // 15*640*48 = 460800 items
        if (id >= 15*NSEQ*48) return;
        int ptIdx = id / (NSEQ*48); int rem = id % (NSEQ*48);
        int n = rem / 48, q = rem % 48;
        int pt = c_ptmap[ptIdx];
        int p = pt / LL, t = pt % LL;
        int b = n / CC, c = n % CC;
        int u = user_index[b];
        int base = ((u*CC + c)*PP + p)*LL + t;
        int col = q*8;
        const float* s;
        if (q < 16){
            int ty = ttype[base]; int pi = tpath[base];
            const float* e = (ty==0)?user_emb:(ty==1)?news_emb:entity_emb;
            s = e + (size_t)pi*DD + col;
        } else if (q < 32){
            s = type_emb + (size_t)ttype[base]*DD + (col-128);
        } else {
            s = relation_emb + (size_t)trel[base]*DD + (col-256);
        }
        float4 x0 = *(const float4*)s, x1 = *(const float4*)(s+4);
        uint4 o;
        o.x = f2bf(x0.x) | ((unsigned)f2bf(x0.y)<<16);
        o.y = f2bf(x0.z) | ((unsigned)f2bf(x0.w)<<16);
        o.z = f2bf(x1.x) | ((unsigned)f2bf(x1.y)<<16);
        o.w = f2bf(x1.z) | ((unsigned)f2bf(x1.w)<<16);
        *(uint4*)(X + (size_t)(pt*NSEQ + n)*IN0 + col) = o;
    } else {
        // ---------------- emb-score dots: embv[n] = <news[cand[n]], user[u(b)]> ----
        int id = (bx - 2785)*256 + threadIdx.x;   // 640*16 = 10240 items
        int n = id >> 4, k = id & 15;
        int b = n / CC;
        int nb = cand[n];
        int u = user_index[b];
        const float4* ne = (const float4*)(news_emb + (size_t)nb*DD + k*8);
        const float4* ue = (const float4*)(user_emb + (size_t)u*DD + k*8);
        float4 a0 = ne[0], a1 = ne[1], u0 = ue[0], u1 = ue[1];
        float v = a0.x*u0.x + a0.y*u0.y + a0.z*u0.z + a0.w*u0.w
                + a1.x*u1.x + a1.y*u1.y + a1.z*u1.z + a1.w*u1.w;
        #pragma unroll
        for (int off=8; off; off>>=1) v += __shfl_down(v, off, 16);
        if (k == 0) embv[n] = v;
    }
}

// ---- tiled MFMA GEMM v6: G0c = X @ Wih0^T, 128-row tiles, async Bs stage ----
// grid: 600 = 15 ptIdx x 5 m128 x 8 nch. Block 512 thr (8 waves x 16 rows).
// Bs staged ONCE per block (vs twice at 64-row tiles) via global_load_lds.
// G0c[tile16][gt][lane][4], tile16 = pt*40 + row/16
__global__ __launch_bounds__(512) void gemm_ih0_v6(const unsigned short* __restrict__ X,
                                                   const unsigned short* __restrict__ F0,
                                                   float* __restrict__ G0c){
    __shared__ __align__(16) unsigned short Bs[12*4*512];   // 48 KB
    int bx = blockIdx.x;
    int nch = bx & 7;
    int m128 = (bx >> 3) % 5;
    int pt  = c_ptmap[bx / 40];
    int p = pt / LL;
    int tid = threadIdx.x, lane = tid & 63, w = tid >> 6;
    int r16 = lane & 15, qd = lane >> 4;

    // async-stage Bs: 6 chunks x 8192 B; each thread 16 B per chunk.
    // dst = wave-uniform base + lane*16 (HW adds lane offset).
    {
        const unsigned short* Fp = F0 + (((size_t)p*12)*32 + nch*4)*512;
        int half = tid >> 8;                 // 0/1, wave-uniform
        int t255 = tid & 255;
        #pragma unroll
        for (int v=0; v<6; v++){
            int jj = v*2 + half;             // j-slab 0..11
            __builtin_amdgcn_global_load_lds(
                (as1_uint*)(Fp + (size_t)jj*32*512 + t255*8),
                (as3_uint*)(Bs + jj*2048 + (t255 & 192)*8),
                16, 0, 0);
        }
    }
    __syncthreads();   // drains global_load_lds

    f32x4 acc[4];
    #pragma unroll
    for (int i=0;i<4;i++) acc[i] = (f32x4)0.0f;
    const unsigned short* Xb = X + ((size_t)pt*NSEQ + m128*128 + w*16 + r16)*IN0 + qd*8;
    #pragma unroll
    for (int kt=0; kt<12; kt++){
        short8 a = *(const short8*)(Xb + kt*32);
        #pragma unroll
        for (int i=0;i<4;i++){
            short8 bfr = *(const short8*)(Bs + (kt*4+i)*512 + lane*8);
            acc[i] = __builtin_amdgcn_mfma_f32_16x16x32_bf16(a, bfr, acc[i], 0,0,0);
        }
    }
    int tile16 = pt*40 + m128*8 + w;
    float* dst = G0c + (((size_t)tile16*32 + nch*4)*64 + lane)*4;
    #pragma unroll
    for (int i=0;i<4;i++)
        *(f32x4*)(dst + (size_t)i*256) = acc[i];
}

// ---- fused 2-layer LSTM v8: async global_load_lds for Whh0 stage,
//      double-buffered h-tiles, 1 barrier/step, last-block fused final -------
// Wave w owns hidden units j = w*16 + (lane&15); frag gt = gate*8 + w so
// acc[0..3] = (i,f,g,o) preacts of unit j for rows qd*4+v.
__global__ __launch_bounds__(512, 2) void lstm_v8(
    const float* __restrict__ G0c,
    const unsigned short* __restrict__ F1,   // Whh0 frags (async-staged to LDS)
    const unsigned short* __restrict__ F2,   // Wih1 frags (reg-cached)
    const unsigned short* __restrict__ F3,   // Whh1 frags (reg-cached)
    const float* __restrict__ b0, const float* __restrict__ b1c,
    const float* __restrict__ W1, const float* __restrict__ b1v,
    const float* __restrict__ W2, const float* __restrict__ b2v,
    float* __restrict__ psum,
    const float* __restrict__ embv, int* __restrict__ ctr,
    float* __restrict__ out){
    // 128 KiB Whh0 fragment slice for this p; epilogue scratch overlays it
    // (safe: last F1s read is hh0 of step p, before step p's barrier).
    __shared__ __align__(16) unsigned short F1s[4*32*512];   // 131072 B
    __shared__ unsigned short h0T[2][16*HPAD];               // 2x 4352 B
    __shared__ unsigned short h1T[2][16*HPAD];
    __shared__ int lastFlag;
    float* h1f  = (float*)F1s;               // [16][132] = 8448 B
    float* mlpb = (float*)(F1s + 16*132*2);  // [16][17]  = 1088 B

    int p = blockIdx.x / 40, nt = blockIdx.x % 40;
    int n0 = nt*16;
    int tid = threadIdx.x;
    int lane = tid & 63, w = tid >> 6;
    int r16 = lane & 15, qd = lane >> 4;
    int j = w*16 + r16;

    // ---- async-stage Whh0 frag slice to LDS (only needed when p>0) ----
    if (p > 0){
        const unsigned short* F1g = F1 + (size_t)p*4*32*512;
        #pragma unroll
        for (int v=0; v<16; v++){
            __builtin_amdgcn_global_load_lds(
                (as1_uint*)(F1g + (size_t)v*4096 + tid*8),
                (as3_uint*)(F1s + v*4096 + (tid & 448)*8),
                16, 0, 0);
        }
    }

    // reg-cache layer-1 weights: frag (kt, gate i) at gt = i*8 + w
    short8 f2r[16], f3r[16];
    {
        const unsigned short* F2p = F2 + (size_t)p*4*32*512 + lane*8;
        const unsigned short* F3p = F3 + (size_t)p*4*32*512 + lane*8;
        #pragma unroll
        for (int kt=0; kt<4; kt++)
            #pragma unroll
            for (int i=0;i<4;i++){
                f2r[kt*4+i] = *(const short8*)(F2p + (size_t)(kt*32 + i*8 + w)*512);
                f3r[kt*4+i] = *(const short8*)(F3p + (size_t)(kt*32 + i*8 + w)*512);
            }
    }
    float bL0[4], bL1[4];
    #pragma unroll
    for (int i=0;i<4;i++){
        int col = (i*8 + w)*16 + r16;
        bL0[i] = b0[p*GATES + col];
        bL1[i] = b1c[p*GATES + col];
    }

    // prefetch slab t=0 (C-layout: this wave's gate tiles gt=i*8+w)
    f32x4 pf[4];
    {
        const float* slab = G0c + (size_t)((p*LL + 0)*40 + nt)*8192;
        #pragma unroll
        for (int i=0;i<4;i++) pf[i] = *(const f32x4*)(slab + ((i*8+w)*64 + lane)*4);
    }
    float c0s[4] = {0,0,0,0}, c1s[4] = {0,0,0,0};

    for (int t=0; t<=p; t++){
        const int cur = t & 1, prv = cur ^ 1;
        // ---- layer 0 preacts: slab + bias (+ h0 @ Whh0^T from LDS) ----
        f32x4 acc[4];
        #pragma unroll
        for (int i=0;i<4;i++){
            f32x4 a = pf[i]; float bb = bL0[i];
            a[0]+=bb; a[1]+=bb; a[2]+=bb; a[3]+=bb; acc[i]=a;
        }
        if (t < p){
            const float* ns = G0c + (size_t)((p*LL + t + 1)*40 + nt)*8192;
            #pragma unroll
            for (int i=0;i<4;i++) pf[i] = *(const f32x4*)(ns + ((i*8+w)*64 + lane)*4);
        }
        if (t > 0){
            #pragma unroll
            for (int kt=0; kt<4; kt++){
                short8 a = *(const short8*)(&h0T[prv][0] + r16*HPAD + kt*32 + qd*8);
                #pragma unroll
                for (int i=0;i<4;i++){
                    short8 bfr = *(const short8*)(F1s + (size_t)(kt*32 + i*8 + w)*512 + lane*8);
                    acc[i] = __builtin_amdgcn_mfma_f32_16x16x32_bf16(a, bfr, acc[i], 0,0,0);
                }
            }
        }
        // ---- combine layer 0 (registers), write h0T[cur] ----
        #pragma unroll
        for (int v=0; v<4; v++){
            float cc = sigf(acc[1][v])*c0s[v] + sigf(acc[0][v])*tanhfast(acc[2][v]);
            c0s[v] = cc;
            h0T[cur][(qd*4+v)*HPAD + j] = f2bf(sigf(acc[3][v])*tanhfast(cc));
        }
        __syncthreads();   // h0T[cur] visible; drains F1s async stage (t=0); h1T[t-1]
        // ---- layer 1 preacts: bias + h0 @ Wih1^T (+ h1 @ Whh1^T), regs ----
        #pragma unroll
        for (int i=0;i<4;i++){
            float bb = bL1[i];
            f32x4 a; a[0]=bb; a[1]=bb; a[2]=bb; a[3]=bb; acc[i]=a;
        }
        #pragma unroll
        for (int kt=0; kt<4; kt++){
            short8 a = *(const short8*)(&h0T[cur][0] + r16*HPAD + kt*32 + qd*8);
            #pragma unroll
            for (int i=0;i<4;i++)
                acc[i] = __builtin_amdgcn_mfma_f32_16x16x32_bf16(a, f2r[kt*4+i], acc[i], 0,0,0);
        }
        if (t > 0){
            #pragma unroll
            for (int kt=0; kt<4; kt++){
                short8 a = *(const short8*)(&h1T[prv][0] + r16*HPAD + kt*32 + qd*8);
                #pragma unroll
                for (int i=0;i<4;i++)
                    acc[i] = __builtin_amdgcn_mfma_f32_16x16x32_bf16(a, f3r[kt*4+i], acc[i], 0,0,0);
            }
        }
        // ---- combine layer 1 (registers), write h1T[cur] ----
        #pragma unroll
        for (int v=0; v<4; v++){
            float cc = sigf(acc[1][v])*c1s[v] + sigf(acc[0][v])*tanhfast(acc[2][v]);
            c1s[v] = cc;
            float hh = sigf(acc[3][v])*tanhfast(cc);
            if (t < p) h1T[cur][(qd*4+v)*HPAD + j] = f2bf(hh);
            else       h1f[(qd*4+v)*132 + j] = hh;
        }
    }
    __syncthreads();
    // ---- scoring MLP: sigmoid(relu(h1@W1^T+b1)@W2^T+b2), mean over paths ----
    if (tid < 256){
        int rr = tid & 15, hc = tid >> 4;
        const float4* w1r = (const float4*)(W1 + hc*DD);
        const float4* hrow = (const float4*)(h1f + rr*132);
        float a0 = b1v[hc], a1 = 0.0f, a2 = 0.0f, a3 = 0.0f;
        #pragma unroll
        for (int k=0;k<32;k++){
            float4 wv = w1r[k];
            float4 hv = hrow[k];
            a0 = fmaf(hv.x, wv.x, a0);
            a1 = fmaf(hv.y, wv.y, a1);
            a2 = fmaf(hv.z, wv.z, a2);
            a3 = fmaf(hv.w, wv.w, a3);
        }
        mlpb[hc*17 + rr] = fmaxf((a0+a1)+(a2+a3), 0.0f);
    }
    __syncthreads();
    if (tid < 16){
        float s = b2v[0];
        #pragma unroll
        for (int h=0;h<16;h++) s = fmaf(mlpb[h*17 + tid], W2[h], s);
        atomicAdd(&psum[n0 + tid], 0.2f*sigf(s));
        __threadfence();   // publish psum before the completion counter
    }
    __syncthreads();
    // ---- last-block fused final: emb_score + running mean ----
    if (tid == 0){
        int old = atomicAdd(ctr, 1);
        lastFlag = (old == 199);
    }
    __syncthreads();
    if (!lastFlag) return;
    float* ps = (float*)F1s;   // reuse LDS (h1f/mlpb dead by now)
    for (int i = tid; i < NSEQ; i += 512)
        ps[i] = atomicAdd(&psum[i], 0.0f);   // coherent cross-XCD read
    __syncthreads();
    if (tid < BB){
        float cum = 0.0f;
        #pragma unroll
        for (int c=0;c<CC;c++){
            cum += ps[tid*CC + c];
            out[tid*CC + c] = sigf(embv[tid*CC + c]) + cum/(float)(c+1);
        }
    }
}

extern "C" void kernel_launch(void* const* d_in, const int* in_sizes, int n_in,
                              void* d_out, int out_size, void* d_ws, size_t ws_size,
                              hipStream_t stream){
    const int* cand        = (const int*)d_in[0];
    const int* uidx        = (const int*)d_in[1];
    const int* tpath       = (const int*)d_in[2];
    const int* ttype       = (const int*)d_in[3];
    const int* trel        = (const int*)d_in[4];
    const float* entity_emb   = (const float*)d_in[5];
    const float* relation_emb = (const float*)d_in[6];
    const float* user_emb     = (const float*)d_in[7];
    const float* news_emb     = (const float*)d_in[8];
    const float* type_emb     = (const float*)d_in[9];
    const float* Wih0 = (const float*)d_in[10];
    const float* Whh0 = (const float*)d_in[11];
    const float* bih0 = (const float*)d_in[12];
    const float* bhh0 = (const float*)d_in[13];
    const float* Wih1 = (const float*)d_in[14];
    const float* Whh1 = (const float*)d_in[15];
    const float* bih1 = (const float*)d_in[16];
    const float* bhh1 = (const float*)d_in[17];
    const float* W1 = (const float*)d_in[18];
    const float* b1 = (const float*)d_in[19];
    const float* W2 = (const float*)d_in[20];
    const float* b2 = (const float*)d_in[21];
    float* out = (float*)d_out;

    char* ws = (char*)d_ws;
    unsigned short* F0 = (unsigned short*)ws;  ws += (size_t)PP*12*32*512*2;   // 1.97 MB
    unsigned short* F1 = (unsigned short*)ws;  ws += (size_t)PP*4*32*512*2;
    unsigned short* F2 = (unsigned short*)ws;  ws += (size_t)PP*4*32*512*2;
    unsigned short* F3 = (unsigned short*)ws;  ws += (size_t)PP*4*32*512*2;
    float* b0  = (float*)ws;                   ws += PP*GATES*4;
    float* b1c = (float*)ws;                   ws += PP*GATES*4;
    unsigned short* X = (unsigned short*)ws;   ws += (size_t)PP*LL*NSEQ*IN0*2; // 12.3 MB
    float* G0c = (float*)ws;                   ws += (size_t)PP*LL*NSEQ*GATES*4; // 32.8 MB
    float* psum = (float*)ws;                  ws += NSEQ*4;
    float* embv = (float*)ws;                  ws += NSEQ*4;
    int*   ctr  = (int*)ws;                    ws += 4;

    stage0_kernel<<<985+1800+40,256,0,stream>>>(Wih0,Whh0,Wih1,Whh1,bih0,bhh0,bih1,bhh1,
                                             F0,F1,F2,F3,b0,b1c,psum,
                                             uidx,tpath,ttype,trel,entity_emb,relation_emb,
                                             user_emb,news_emb,type_emb,X,
                                             cand,embv,ctr);
    gemm_ih0_v6<<<600,512,0,stream>>>(X, F0, G0c);
    lstm_v8<<<200,512,0,stream>>>(G0c, F1, F2, F3, b0, b1c, W1, b1, W2, b2,
                                  psum, embv, ctr, out);
}